// Round 1
// baseline (256.359 us; speedup 1.0000x reference)
//
#include <hip/hip_runtime.h>

// Problem constants (match reference)
#define BB 32
#define SS 2048
#define DD 512
#define VEC_PER_ROW (DD / 4)   // 128 float4 per (b,s) position

// ---------------------------------------------------------------------------
// Phase 1: per-row inclusive scan of masks -> rank array in workspace.
// rank[b*S+s] = (cumsum(mask[b,:s+1]) - 1) if mask else -1.
// One block per row (32 blocks, 256 threads, 8 elems/thread).
//
// Mask dtype is a JAX bool; the harness may have uploaded it as int32,
// float32, or raw 1-byte bools. Detect on-device: scan first 16384 dwords
// (= 64 KiB, safe under every layout since the smallest possible buffer is
// 65536 bytes). If any dword is outside {0, 1, 0x3f800000}, the buffer must
// be byte-packed bools; otherwise 4-byte elements where nonzero dword <=>
// mask true (covers int32 0/1 and float32 0.0/1.0). Deterministic.
// ---------------------------------------------------------------------------
__global__ void pe_rank_kernel(const unsigned int* __restrict__ m32,
                               int* __restrict__ rank_out) {
    const int b = blockIdx.x;
    const int t = threadIdx.x;

    __shared__ int flag_byte;
    if (t == 0) flag_byte = 0;
    __syncthreads();
    for (int i = t; i < 16384; i += 256) {
        unsigned int v = m32[i];
        if (v != 0u && v != 1u && v != 0x3f800000u) flag_byte = 1;  // benign race
    }
    __syncthreads();
    const int is_byte = flag_byte;
    const unsigned char* m8 = (const unsigned char*)m32;

    __shared__ int psum[256];
    const int PER = SS / 256;  // 8
    int vals[PER];
    int s = 0;
#pragma unroll
    for (int i = 0; i < PER; ++i) {
        const int idx = b * SS + t * PER + i;
        const int mv = is_byte ? (m8[idx] != 0) : (m32[idx] != 0u);
        vals[i] = mv;
        s += mv;
    }
    psum[t] = s;
    __syncthreads();
    // Hillis-Steele inclusive scan over 256 per-thread sums
    for (int off = 1; off < 256; off <<= 1) {
        const int v = (t >= off) ? psum[t - off] : 0;
        __syncthreads();
        psum[t] += v;
        __syncthreads();
    }
    int run = psum[t] - s;  // exclusive prefix for this thread
#pragma unroll
    for (int i = 0; i < PER; ++i) {
        run += vals[i];
        // masked position: rank = run-1 in [0, SS-1] (SS == MAX_LEN, no clip
        // needed); unmasked: -1 sentinel
        rank_out[b * SS + t * PER + i] = vals[i] ? (run - 1) : -1;
    }
}

// ---------------------------------------------------------------------------
// Phase 2: streaming float4 add. One thread per 16B chunk, grid-stride.
// rank[row] is shared by 128 consecutive threads -> cache broadcast.
// ---------------------------------------------------------------------------
__global__ void pe_add_kernel(const float4* __restrict__ seqs,
                              const int* __restrict__ rank,
                              const float4* __restrict__ pe,
                              float4* __restrict__ out) {
    const int total = BB * SS * VEC_PER_ROW;
    const int stride = gridDim.x * blockDim.x;
    for (int idx = blockIdx.x * blockDim.x + threadIdx.x; idx < total;
         idx += stride) {
        const int row = idx >> 7;   // / VEC_PER_ROW
        const int v   = idx & (VEC_PER_ROW - 1);
        float4 sv = seqs[idx];
        const int rk = rank[row];
        if (rk >= 0) {
            const float4 pv = pe[(rk << 7) + v];
            sv.x += pv.x;
            sv.y += pv.y;
            sv.z += pv.z;
            sv.w += pv.w;
        }
        out[idx] = sv;
    }
}

extern "C" void kernel_launch(void* const* d_in, const int* in_sizes, int n_in,
                              void* d_out, int out_size, void* d_ws, size_t ws_size,
                              hipStream_t stream) {
    const float* seqs        = (const float*)d_in[0];
    const unsigned int* msks = (const unsigned int*)d_in[1];
    const float* pe          = (const float*)d_in[2];
    float* out               = (float*)d_out;
    int* rank                = (int*)d_ws;  // 32*2048*4 = 256 KiB

    pe_rank_kernel<<<BB, 256, 0, stream>>>(msks, rank);

    // memory-bound: cap grid at ~2048 blocks, grid-stride the rest (G11)
    pe_add_kernel<<<2048, 256, 0, stream>>>(
        (const float4*)seqs, rank, (const float4*)pe, (float4*)out);
}

// Round 5
// 244.576 us; speedup vs baseline: 1.0482x; 1.0482x over previous
//
#include <hip/hip_runtime.h>

// Problem constants (match reference)
#define BB 32
#define SS 2048
#define DD 512
#define V4_PER_ROW (DD / 4)            // 128 float4 per (b,s) row
#define TOTAL (BB * SS * V4_PER_ROW)   // 8388608 float4
#define TPB 256
#define GRID 2048
#define STRIDE (GRID * TPB)            // 524288 (multiple of 128 -> wave-uniform rows)
#define ITERS (TOTAL / STRIDE)         // 16
#define ROWSTEP (STRIDE / V4_PER_ROW)  // 4096 rows per grid-stride step

// native clang vector type — required by __builtin_nontemporal_load/store
typedef float f32x4 __attribute__((ext_vector_type(4)));

// ---------------------------------------------------------------------------
// Phase 1: per-row inclusive scan of masks -> rank array in workspace.
// rank[b*S+s] = (cumsum(mask[b,:s+1]) - 1) if mask else -1.
// One block per row (32 blocks, 1024 threads, 2 elems/thread).
//
// Mask dtype detection (JAX bool may arrive as int32/float32/byte-packed):
// scan first 8192 dwords; any dword outside {0,1,0x3f800000} => byte layout.
// 8192 dwords is in-bounds under every layout (byte layout = 16384 dwords).
// ---------------------------------------------------------------------------
__global__ __launch_bounds__(1024) void pe_rank_kernel(
    const unsigned int* __restrict__ m32, int* __restrict__ rank_out) {
    const int b = blockIdx.x;
    const int t = threadIdx.x;

    __shared__ int flag_byte;
    if (t == 0) flag_byte = 0;
    __syncthreads();
    for (int i = t; i < 8192; i += 1024) {
        unsigned int v = m32[i];
        if (v != 0u && v != 1u && v != 0x3f800000u) flag_byte = 1;  // benign race
    }
    __syncthreads();
    const int is_byte = flag_byte;
    const unsigned char* m8 = (const unsigned char*)m32;

    __shared__ int psum[1024];
    const int PER = SS / 1024;  // 2
    int vals[PER];
    int s = 0;
#pragma unroll
    for (int i = 0; i < PER; ++i) {
        const int idx = b * SS + t * PER + i;
        const int mv = is_byte ? (m8[idx] != 0) : (m32[idx] != 0u);
        vals[i] = mv;
        s += mv;
    }
    psum[t] = s;
    __syncthreads();
    // Hillis-Steele inclusive scan over 1024 per-thread sums
    for (int off = 1; off < 1024; off <<= 1) {
        const int v = (t >= off) ? psum[t - off] : 0;
        __syncthreads();
        psum[t] += v;
        __syncthreads();
    }
    int run = psum[t] - s;  // exclusive prefix for this thread
#pragma unroll
    for (int i = 0; i < PER; ++i) {
        run += vals[i];
        rank_out[b * SS + t * PER + i] = vals[i] ? (run - 1) : -1;
    }
}

// ---------------------------------------------------------------------------
// Phase 2: streaming float4 add, fully unrolled 16 iters in 4 groups of 4.
//  - rank loads are wave-uniform -> readfirstlane + SGPR loads (SMEM pipe)
//  - group-of-4 issue: ~8KB outstanding vector loads per wave
//  - branchless pe: rc=max(r,0), scale by 0/1 -> straight-line code
//  - nontemporal seqs/out: don't evict the hot 4MB pe table from L2/L3
// ---------------------------------------------------------------------------
__global__ __launch_bounds__(TPB) void pe_add_kernel(
    const f32x4* __restrict__ seqs, const int* __restrict__ rank,
    const f32x4* __restrict__ pe, f32x4* __restrict__ out) {
    const int tid = blockIdx.x * TPB + threadIdx.x;
    const int col = tid & (V4_PER_ROW - 1);            // loop-invariant
    const int rowbase = __builtin_amdgcn_readfirstlane(tid >> 7);

#pragma unroll
    for (int g = 0; g < ITERS / 4; ++g) {
        const int k = 4 * g;
        // scalar rank loads (wave-uniform), issued up front
        const int r0 = rank[rowbase + (k + 0) * ROWSTEP];
        const int r1 = rank[rowbase + (k + 1) * ROWSTEP];
        const int r2 = rank[rowbase + (k + 2) * ROWSTEP];
        const int r3 = rank[rowbase + (k + 3) * ROWSTEP];
        // streamed seqs loads, all 4 in flight
        const f32x4 a0 = __builtin_nontemporal_load(&seqs[tid + (k + 0) * STRIDE]);
        const f32x4 a1 = __builtin_nontemporal_load(&seqs[tid + (k + 1) * STRIDE]);
        const f32x4 a2 = __builtin_nontemporal_load(&seqs[tid + (k + 2) * STRIDE]);
        const f32x4 a3 = __builtin_nontemporal_load(&seqs[tid + (k + 3) * STRIDE]);
        // branchless pe gathers (unmasked rows read pe row 0, L1/L2 hit)
        const int rc0 = r0 < 0 ? 0 : r0;
        const int rc1 = r1 < 0 ? 0 : r1;
        const int rc2 = r2 < 0 ? 0 : r2;
        const int rc3 = r3 < 0 ? 0 : r3;
        const f32x4 p0 = pe[(rc0 << 7) + col];
        const f32x4 p1 = pe[(rc1 << 7) + col];
        const f32x4 p2 = pe[(rc2 << 7) + col];
        const f32x4 p3 = pe[(rc3 << 7) + col];
        const float f0 = r0 < 0 ? 0.0f : 1.0f;
        const float f1 = r1 < 0 ? 0.0f : 1.0f;
        const float f2 = r2 < 0 ? 0.0f : 1.0f;
        const float f3 = r3 < 0 ? 0.0f : 1.0f;
        f32x4 o0, o1, o2, o3;
        o0 = a0; o0 += p0 * f0;
        o1 = a1; o1 += p1 * f1;
        o2 = a2; o2 += p2 * f2;
        o3 = a3; o3 += p3 * f3;
        __builtin_nontemporal_store(o0, &out[tid + (k + 0) * STRIDE]);
        __builtin_nontemporal_store(o1, &out[tid + (k + 1) * STRIDE]);
        __builtin_nontemporal_store(o2, &out[tid + (k + 2) * STRIDE]);
        __builtin_nontemporal_store(o3, &out[tid + (k + 3) * STRIDE]);
    }
}

extern "C" void kernel_launch(void* const* d_in, const int* in_sizes, int n_in,
                              void* d_out, int out_size, void* d_ws, size_t ws_size,
                              hipStream_t stream) {
    const float* seqs        = (const float*)d_in[0];
    const unsigned int* msks = (const unsigned int*)d_in[1];
    const float* pe          = (const float*)d_in[2];
    float* out               = (float*)d_out;
    int* rank                = (int*)d_ws;  // 32*2048*4 = 256 KiB

    pe_rank_kernel<<<BB, 1024, 0, stream>>>(msks, rank);
    pe_add_kernel<<<GRID, TPB, 0, stream>>>(
        (const f32x4*)seqs, rank, (const f32x4*)pe, (f32x4*)out);
}